// Round 1
// 253.220 us; speedup vs baseline: 1.0473x; 1.0473x over previous
//
#include <hip/hip_runtime.h>
#include <hip/hip_bf16.h>
#include <cstdint>
#include <cstddef>

// B=4, S=2048, D=1024, H=16, DH=64, M = B*S = 8192
#define S_ 2048
#define D_ 1024
#define H_ 16
#define DH_ 64
#define M_ 8192

using bf16 = __bf16;
using bf16x4 = __attribute__((ext_vector_type(4))) __bf16;
using bf16x8 = __attribute__((ext_vector_type(8))) __bf16;
using f32x4 = __attribute__((ext_vector_type(4))) float;
using s16x4 = __attribute__((ext_vector_type(4))) short;

__device__ __forceinline__ void g2lds16(const bf16* g, bf16* l) {
  __builtin_amdgcn_global_load_lds(
      (const __attribute__((address_space(1))) void*)g,
      (__attribute__((address_space(3))) void*)l, 16, 0, 0);
}

// 16x16x16 bf16 MFMA (used by attn PV)
__device__ __forceinline__ f32x4 mfma16(bf16x4 a, bf16x4 b, f32x4 c) {
#if __has_builtin(__builtin_amdgcn_mfma_f32_16x16x16_bf16)
  return __builtin_amdgcn_mfma_f32_16x16x16_bf16(a, b, c, 0, 0, 0);
#elif __has_builtin(__builtin_amdgcn_mfma_f32_16x16x16bf16_1k)
  return __builtin_amdgcn_mfma_f32_16x16x16bf16_1k(
      __builtin_bit_cast(s16x4, a), __builtin_bit_cast(s16x4, b), c, 0, 0, 0);
#else
  f32x4 d;
  asm("v_mfma_f32_16x16x16_bf16 %0, %1, %2, %3"
      : "=v"(d)
      : "v"(a), "v"(b), "v"(c));
  return d;
#endif
}

// ------- fused fp32->bf16 converts: x (blocks 0..4095) + 4 weights^T -------
__global__ __launch_bounds__(256) void cvt_all_kernel(
    const float* __restrict__ x, const float* __restrict__ w0,
    const float* __restrict__ w1, const float* __restrict__ w2,
    const float* __restrict__ w3, bf16* __restrict__ xb,
    bf16* __restrict__ o0, bf16* __restrict__ o1, bf16* __restrict__ o2,
    bf16* __restrict__ o3) {
  __shared__ float tile[32][33];
  int bx = blockIdx.x;
  int tid = threadIdx.x;
  if (bx < 4096) {
    size_t i = ((size_t)bx * 256 + tid) * 8;
    float4 a = *(const float4*)(x + i);
    float4 b = *(const float4*)(x + i + 4);
    bf16x8 o;
    o[0] = (bf16)a.x; o[1] = (bf16)a.y; o[2] = (bf16)a.z; o[3] = (bf16)a.w;
    o[4] = (bf16)b.x; o[5] = (bf16)b.y; o[6] = (bf16)b.z; o[7] = (bf16)b.w;
    *(bf16x8*)(xb + i) = o;
    return;
  }
  int wb = bx - 4096;
  int wsel = wb >> 10; wb &= 1023;
  const float* W; bf16* O;
  switch (wsel) {
    case 0: W = w0; O = o0; break;
    case 1: W = w1; O = o1; break;
    case 2: W = w2; O = o2; break;
    default: W = w3; O = o3; break;
  }
  int n0 = (wb & 31) * 32;
  int k0 = (wb >> 5) * 32;
#pragma unroll
  for (int i = 0; i < 4; ++i) {
    int e = tid + i * 256; int rr = e >> 5, cc = e & 31;
    tile[rr][cc] = W[(size_t)(k0 + rr) * 1024 + n0 + cc];
  }
  __syncthreads();
#pragma unroll
  for (int i = 0; i < 4; ++i) {
    int e = tid + i * 256; int rr = e >> 5, cc = e & 31;
    O[(size_t)(n0 + rr) * 1024 + k0 + cc] = (bf16)tile[cc][rr];
  }
}

// ------- GEMM v4: 128x256 tile, BK=64, 8 waves (2M x 4N, 64x64 each),
// TRIPLE-buffered LDS (3 x 48KB dynamic) with prefetch distance = 2 K-tiles.
// One s_waitcnt vmcnt(6)+s_barrier per K-tile (6 loads of tile t+2 stay in
// flight; never drains to 0 in the main loop) -> load latency fully hidden
// under 2 tiles (~800cy) of MFMA. 2 phases/tile (k-step 0/1), setprio(1)
// around each 16-MFMA cluster (T5). Staging is XOR-swizzled on the GLOBAL
// source (chunk c -> c^(row&7)); readers use the same involution ->
// <=2-way LDS banking (free). MODE0: Q/K/V (N=3x1024, grid 768 = 3 exact
// CU rounds). MODE1: ctx@W_O + residual (grid 256 = 1 round).
template <int MODE>
__global__ __launch_bounds__(512, 2) void gemm_kernel(
    const bf16* __restrict__ A,
    const bf16* __restrict__ Bt0, const bf16* __restrict__ Bt1,
    const bf16* __restrict__ Bt2,
    bf16* __restrict__ Qo, bf16* __restrict__ Ko, bf16* __restrict__ Vto,
    const float* __restrict__ xres, float* __restrict__ out) {
  extern __shared__ float4 smem4[];
  bf16* smem = (bf16*)smem4;  // 3 buffers x 24576 elems (A 8192 + B 16384)

  constexpr int NWG = (MODE == 0) ? 768 : 256;
  constexpr int CPX = NWG / 8;
  constexpr int NBN = (MODE == 0) ? 12 : 4;
  const int wg = ((int)blockIdx.x & 7) * CPX + ((int)blockIdx.x >> 3);
  const int bn = wg % NBN, bm = wg / NBN;

  const bf16* Bt;
  int n0full = 0, wsel = 0;
  if constexpr (MODE == 0) {
    wsel = bn >> 2;
    Bt = (wsel == 0) ? Bt0 : (wsel == 1 ? Bt1 : Bt2);
    n0full = (bn & 3) * 256;
  } else {
    Bt = Bt0;
    n0full = bn * 256;
  }

  const int tid = threadIdx.x;
  const int wave = tid >> 6, lane = tid & 63;
  const int quad = lane >> 4, r = lane & 15;
  const int wm = (wave >> 2) * 64, wn = (wave & 3) * 64;

  // ---- staging setup: 6 x 1KB-slab loads per thread per K-tile ----
  // slab = 8 rows x 128B; lane l -> row l>>3, LDS chunk l&7, global chunk
  // (l&7)^(l>>3)  (pre-swizzled source; LDS stays linear for global_load_lds)
  const int lrow = lane >> 3;
  const int lcol = ((lane & 7) ^ lrow) * 8;  // elements
  const int am0 = bm * 128 + wave * 8 + lrow;
  const int am1 = am0 + 64;
  const bf16 *p0, *p1, *p2, *p3, *p4, *p5;
  if constexpr (MODE == 0) {
    p0 = A + (size_t)am0 * 1024 + lcol;
    p1 = A + (size_t)am1 * 1024 + lcol;
  } else {
    // A is ctx [B,H,S,DH]; K-tile kt == head kt (64-wide tiles).
    p0 = A + (size_t)(am0 >> 11) * (16 * (size_t)S_ * DH_) +
         (size_t)(am0 & 2047) * 64 + lcol;
    p1 = A + (size_t)(am1 >> 11) * (16 * (size_t)S_ * DH_) +
         (size_t)(am1 & 2047) * 64 + lcol;
  }
  const int bnr = n0full + wave * 8 + lrow;
  p2 = Bt + (size_t)bnr * 1024 + lcol;
  p3 = Bt + (size_t)(bnr + 64) * 1024 + lcol;
  p4 = Bt + (size_t)(bnr + 128) * 1024 + lcol;
  p5 = Bt + (size_t)(bnr + 192) * 1024 + lcol;
  constexpr ptrdiff_t dA = (MODE == 0) ? 64 : (ptrdiff_t)S_ * DH_;

  const int oA0 = wave * 512, oA1 = (8 + wave) * 512;
  const int oB0 = 8192 + wave * 512, oB1 = 8192 + (8 + wave) * 512;
  const int oB2 = 8192 + (16 + wave) * 512, oB3 = 8192 + (24 + wave) * 512;

  auto stage = [&](bf16* base) {
    g2lds16(p0, base + oA0); p0 += dA;
    g2lds16(p1, base + oA1); p1 += dA;
    g2lds16(p2, base + oB0); p2 += 64;
    g2lds16(p3, base + oB1); p3 += 64;
    g2lds16(p4, base + oB2); p4 += 64;
    g2lds16(p5, base + oB3); p5 += 64;
  };

  f32x4 acc[4][4];
  const f32x4 zero = {0.f, 0.f, 0.f, 0.f};
#pragma unroll
  for (int i = 0; i < 4; ++i)
#pragma unroll
    for (int j = 0; j < 4; ++j) acc[i][j] = zero;

  // reader addressing (elements). row&7 == r&7 for all frag rows.
  const int rw = r & 7;
  const int x0 = (quad ^ rw) * 8;        // k-step 0 chunk position
  const int x1 = ((quad + 4) ^ rw) * 8;  // k-step 1
  const int raB = (wm + r) * 64;         // + mf*1024
  const int rbB = (wn + r) * 64;         // + nf*1024

  auto phases = [&](const bf16* buf) {
    const bf16* bA = buf;
    const bf16* bB = buf + 8192;
    bf16x8 af[4], bg[4];
    // ---- phase 1: k 0..31
#pragma unroll
    for (int i = 0; i < 4; ++i)
      af[i] = *(const bf16x8*)(bA + raB + i * 1024 + x0);
#pragma unroll
    for (int j = 0; j < 4; ++j)
      bg[j] = *(const bf16x8*)(bB + rbB + j * 1024 + x0);
    __builtin_amdgcn_s_setprio(1);
#pragma unroll
    for (int i = 0; i < 4; ++i)
#pragma unroll
      for (int j = 0; j < 4; ++j)
        acc[i][j] = __builtin_amdgcn_mfma_f32_16x16x32_bf16(af[i], bg[j],
                                                            acc[i][j], 0, 0, 0);
    __builtin_amdgcn_s_setprio(0);
    asm volatile("s_barrier" ::: "memory");
    // ---- phase 2: k 32..63
#pragma unroll
    for (int i = 0; i < 4; ++i)
      af[i] = *(const bf16x8*)(bA + raB + i * 1024 + x1);
#pragma unroll
    for (int j = 0; j < 4; ++j)
      bg[j] = *(const bf16x8*)(bB + rbB + j * 1024 + x1);
    __builtin_amdgcn_s_setprio(1);
#pragma unroll
    for (int i = 0; i < 4; ++i)
#pragma unroll
      for (int j = 0; j < 4; ++j)
        acc[i][j] = __builtin_amdgcn_mfma_f32_16x16x32_bf16(af[i], bg[j],
                                                            acc[i][j], 0, 0, 0);
    __builtin_amdgcn_s_setprio(0);
  };

  bf16* b0 = smem;
  bf16* b1 = smem + 24576;
  bf16* b2 = smem + 49152;

  // prologue: tiles 0,1
  stage(b0);
  stage(b1);

  // K = 1024 -> 16 tiles. Boundary of tile t: wait vmcnt(6) (tile t landed,
  // tile t+1's 6 loads stay in flight), then stage tile t+2.
#pragma unroll 1
  for (int kt = 0; kt < 15; kt += 3) {
    asm volatile("s_waitcnt vmcnt(6)\n\ts_barrier" ::: "memory");
    stage(b2);                    // tile kt+2
    phases(b0);                   // tile kt
    asm volatile("s_waitcnt vmcnt(6)\n\ts_barrier" ::: "memory");
    stage(b0);                    // tile kt+3
    phases(b1);                   // tile kt+1
    asm volatile("s_waitcnt vmcnt(6)\n\ts_barrier" ::: "memory");
    if (kt < 12) stage(b1);       // tile kt+4 (skip nonexistent tile 16)
    phases(b2);                   // tile kt+2
  }
  asm volatile("s_waitcnt vmcnt(0)\n\ts_barrier" ::: "memory");
  phases(b0);                     // tile 15

  // ---- epilogue ----
  const int mB = bm * 128 + wm + quad * 4;  // + mf*16 + g
  if constexpr (MODE == 0) {
    if (wsel < 2) {
      bf16* dst = (wsel == 0) ? Qo : Ko;
#pragma unroll
      for (int i = 0; i < 4; ++i) {
#pragma unroll
        for (int j = 0; j < 4; ++j) {
          int n = n0full + wn + j * 16 + r;
          int h = n >> 6, dh = n & 63;
#pragma unroll
          for (int g = 0; g < 4; ++g) {
            int m = mB + i * 16 + g;
            int b = m >> 11, s = m & 2047;
            dst[((size_t)(b * H_ + h) * S_ + s) * DH_ + dh] =
                (bf16)acc[i][j][g];
          }
        }
      }
    } else {  // V: store transposed [B,H,DH,S]; 4 g's are s-consecutive
#pragma unroll
      for (int i = 0; i < 4; ++i) {
        int m = mB + i * 16;
        int b = m >> 11, s = m & 2047;
#pragma unroll
        for (int j = 0; j < 4; ++j) {
          int n = n0full + wn + j * 16 + r;
          int h = n >> 6, dh = n & 63;
          bf16x4 pk;
#pragma unroll
          for (int g = 0; g < 4; ++g) pk[g] = (bf16)acc[i][j][g];
          *(bf16x4*)(Vto + ((size_t)(b * H_ + h) * DH_ + dh) * S_ + s) = pk;
        }
      }
    }
  } else {
#pragma unroll
    for (int i = 0; i < 4; ++i) {
#pragma unroll
      for (int j = 0; j < 4; ++j) {
        int n = bn * 256 + wn + j * 16 + r;
#pragma unroll
        for (int g = 0; g < 4; ++g) {
          int m = mB + i * 16 + g;
          size_t idx = (size_t)m * 1024 + n;
          out[idx] = acc[i][j][g] + xres[idx];
        }
      }
    }
  }
}

// ------ flash attention v5: 32q/wave, register P (no LDS transpose) ------
// grid = 512: bh = bx & 63 (XCD-local), p = bx >> 6 pairs 128-q tiles
// (p, 15-p): 34 kv-64 iters each. S^T C-layout == A-operand layout of
// 16x16x16 MFMA -> PV directly from registers. Static-max softmax.
__global__ __launch_bounds__(256) void attn_kernel(const bf16* __restrict__ Qb,
                                                   const bf16* __restrict__ Kb,
                                                   const bf16* __restrict__ Vtb,
                                                   bf16* __restrict__ ctx) {
  __shared__ __align__(16) bf16 smK[2][64 * 64];
  __shared__ __align__(16) bf16 smV[2][64 * 64];
  const int bh = blockIdx.x & 63, p = blockIdx.x >> 6;
  const bf16* Qh = Qb + (size_t)bh * S_ * DH_;
  const bf16* Kh = Kb + (size_t)bh * S_ * DH_;
  const bf16* Vh = Vtb + (size_t)bh * DH_ * S_;
  bf16* Ch = ctx + (size_t)bh * S_ * DH_;
  const int tid = threadIdx.x, wave = tid >> 6, lane = tid & 63;
  const int quad = lane >> 4, r = lane & 15;
  const int r7 = r & 7;
  const int c0 = 2 * wave, c1 = c0 + 1;
  const int sr = lane >> 3;
  const int gcol = ((lane & 7) ^ (sr & 7)) * 8;  // source-side XOR swizzle
  const f32x4 zero = {0.f, 0.f, 0.f, 0.f};
  const int xk0 = (quad ^ r7) * 8, xk1 = ((quad + 4) ^ r7) * 8;

  for (int ph = 0; ph < 2; ++ph) {
    const int i128 = ph ? (15 - p) : p;
    const int qB = i128 * 128;
    const int q0w = qB + wave * 32;
    const int numkt = 2 * i128 + 2;

    bf16x8 qf[2][2];
    const float qsc = 0.125f * 1.44269504f;  // 1/sqrt(64) * log2(e)
#pragma unroll
    for (int qg = 0; qg < 2; ++qg)
#pragma unroll
      for (int hh = 0; hh < 2; ++hh) {
        bf16x8 q = *(const bf16x8*)(Qh + (size_t)(q0w + qg * 16 + r) * DH_ +
                                    hh * 32 + quad * 8);
#pragma unroll
        for (int i = 0; i < 8; ++i) q[i] = (bf16)((float)q[i] * qsc);
        qf[qg][hh] = q;
      }

    f32x4 lacc[2] = {zero, zero};
    f32x4 oacc[2][4];
#pragma unroll
    for (int qg = 0; qg < 2; ++qg)
#pragma unroll
      for (int tn = 0; tn < 4; ++tn) oacc[qg][tn] = zero;

    // prologue: tile 0 -> buffer 0
    g2lds16(Kh + (size_t)(c0 * 8 + sr) * DH_ + gcol, &smK[0][c0 * 512]);
    g2lds16(Kh + (size_t)(c1 * 8 + sr) * DH_ + gcol, &smK[0][c1 * 512]);
    g2lds16(Vh + (size_t)(c0 * 8 + sr) * S_ + gcol, &smV[0][c0 * 512]);
    g2lds16(Vh + (size_t)(c1 * 8 + sr) * S_ + gcol, &smV[0][c1 * 512]);

    for (int kt = 0; kt < numkt; ++kt) {
      const int cur = kt & 1;
      const int kv0 = kt * 64;
      if (kt + 1 < numkt) {  // prefetch next tile into other buffer
        const int nk = kv0 + 64;
        g2lds16(Kh + (size_t)(nk + c0 * 8 + sr) * DH_ + gcol, &smK[1 - cur][c0 * 512]);
        g2lds16(Kh + (size_t)(nk + c1 * 8 + sr) * DH_ + gcol, &smK[1 - cur][c1 * 512]);
        g2lds16(Vh + (size_t)(c0 * 8 + sr) * S_ + nk + gcol, &smV[1 - cur][c0 * 512]);
        g2lds16(Vh + (size_t)(c1 * 8 + sr) * S_ + nk + gcol, &smV[1 - cur][c1 * 512]);
        asm volatile("s_waitcnt vmcnt(4)\n\ts_barrier" ::: "memory");
      } else {
        asm volatile("s_waitcnt vmcnt(0)\n\ts_barrier" ::: "memory");
      }
      if (kv0 <= q0w + 31) {  // wave not fully masked for this kv tile
        const bf16* kb = &smK[cur][0];
        const bf16* vb = &smV[cur][0];

        // S^T: s[qg][t][g] = S[kv=kv0+t*16+quad*4+g][q=q0w+qg*16+r]
        f32x4 s[2][4];
#pragma unroll
        for (int t = 0; t < 4; ++t) {
          bf16x8 kf0 = *(const bf16x8*)(kb + (t * 16 + r) * 64 + xk0);
          bf16x8 kf1 = *(const bf16x8*)(kb + (t * 16 + r) * 64 + xk1);
#pragma unroll
          for (int qg = 0; qg < 2; ++qg) {
            f32x4 z = __builtin_amdgcn_mfma_f32_16x16x32_bf16(kf0, qf[qg][0],
                                                              zero, 0, 0, 0);
            s[qg][t] = __builtin_amdgcn_mfma_f32_16x16x32_bf16(kf1, qf[qg][1],
                                                               z, 0, 0, 0);
          }
        }
        if (kt >= numkt - 2) {  // diagonal region: causal mask
#pragma unroll
          for (int qg = 0; qg < 2; ++qg) {
            const int q = q0w + qg * 16 + r;
#pragma unroll
            for (int t = 0; t < 4; ++t) {
              const int kv = kv0 + t * 16 + quad * 4;
#pragma unroll
              for (int g = 0; g < 4; ++g)
                if (kv + g > q) s[qg][t][g] = -1e30f;
            }
          }
        }
        // P = exp2(s); l accumulate; PV via 16x16x16 MFMA (P from registers)
#pragma unroll
        for (int t = 0; t < 4; ++t) {
          bf16x4 pa[2];
#pragma unroll
          for (int qg = 0; qg < 2; ++qg) {
#pragma unroll
            for (int g = 0; g < 4; ++g)
              s[qg][t][g] = __builtin_amdgcn_exp2f(s[qg][t][g]);
            lacc[qg] += s[qg][t];
            bf16x4 pk;
#pragma unroll
            for (int g = 0; g < 4; ++g) pk[g] = (bf16)s[qg][t][g];
            pa[qg] = pk;
          }
#pragma unroll
          for (int tn = 0; tn < 4; ++tn) {
            bf16x4 vf = *(const bf16x4*)(
                vb + (tn * 16 + r) * 64 +
                ((2 * t + (quad >> 1)) ^ r7) * 8 + (quad & 1) * 4);
            oacc[0][tn] = mfma16(pa[0], vf, oacc[0][tn]);
            oacc[1][tn] = mfma16(pa[1], vf, oacc[1][tn]);
          }
        }
      }
      // all waves done reading cur buffers before next iter overwrites them
      asm volatile("s_waitcnt lgkmcnt(0)\n\ts_barrier" ::: "memory");
    }

    // epilogue: reduce l per q (= lane r) per qg, normalize, store
#pragma unroll
    for (int qg = 0; qg < 2; ++qg) {
      float rs = (lacc[qg][0] + lacc[qg][1]) + (lacc[qg][2] + lacc[qg][3]);
      rs += __shfl_xor(rs, 16, 64);
      rs += __shfl_xor(rs, 32, 64);
      const float inv = 1.f / rs;
      f32x4 ib;
#pragma unroll
      for (int g = 0; g < 4; ++g) ib[g] = __shfl(inv, quad * 4 + g, 64);
#pragma unroll
      for (int tn = 0; tn < 4; ++tn) {
        f32x4 ov = oacc[qg][tn] * ib;
#pragma unroll
        for (int g = 0; g < 4; ++g)
          Ch[(size_t)(q0w + qg * 16 + quad * 4 + g) * DH_ + tn * 16 + r] =
              (bf16)ov[g];
      }
    }
  }
}

// ---------------- LayerNorm in-place on d_out ----------------
__global__ __launch_bounds__(256) void ln_kernel(float* __restrict__ out,
                                                 const float* __restrict__ gamma,
                                                 const float* __restrict__ beta) {
  __shared__ float red[8];
  size_t row = blockIdx.x;
  float* p = out + row * 1024;
  int tid = threadIdx.x;
  float4 v = ((const float4*)p)[tid];
  float s1 = v.x + v.y + v.z + v.w;
  float s2 = v.x * v.x + v.y * v.y + v.z * v.z + v.w * v.w;
#pragma unroll
  for (int o = 1; o < 64; o <<= 1) {
    s1 += __shfl_xor(s1, o, 64);
    s2 += __shfl_xor(s2, o, 64);
  }
  int wave = tid >> 6, lane = tid & 63;
  if (lane == 0) { red[wave] = s1; red[4 + wave] = s2; }
  __syncthreads();
  s1 = red[0] + red[1] + red[2] + red[3];
  s2 = red[4] + red[5] + red[6] + red[7];
  float mean = s1 * (1.f / 1024.f);
  float var = s2 * (1.f / 1024.f) - mean * mean;
  float rstd = rsqrtf(var + 1e-5f);
  float4 g = ((const float4*)gamma)[tid];
  float4 b = ((const float4*)beta)[tid];
  float4 o;
  o.x = (v.x - mean) * rstd * g.x + b.x;
  o.y = (v.y - mean) * rstd * g.y + b.y;
  o.z = (v.z - mean) * rstd * g.z + b.z;
  o.w = (v.w - mean) * rstd * g.w + b.w;
  ((float4*)p)[tid] = o;
}

extern "C" void kernel_launch(void* const* d_in, const int* in_sizes, int n_in,
                              void* d_out, int out_size, void* d_ws,
                              size_t ws_size, hipStream_t stream) {
  (void)in_sizes; (void)n_in; (void)out_size; (void)ws_size;
  const float* x  = (const float*)d_in[0];
  const float* WQ = (const float*)d_in[1];
  const float* WK = (const float*)d_in[2];
  const float* WV = (const float*)d_in[3];
  const float* WO = (const float*)d_in[4];
  const float* gamma = (const float*)d_in[5];
  const float* beta  = (const float*)d_in[6];
  float* out = (float*)d_out;

  bf16* ws = (bf16*)d_ws;
  const size_t MD = (size_t)M_ * D_;
  const size_t WW = (size_t)D_ * D_;
  bf16* xb   = ws;
  bf16* wqt  = xb + MD;
  bf16* wkt  = wqt + WW;
  bf16* wvt  = wkt + WW;
  bf16* wot  = wvt + WW;
  bf16* Qb   = wot + WW;
  bf16* Kb   = Qb + MD;
  bf16* Vtb  = Kb + MD;
  bf16* ctxb = Vtb + MD;

  constexpr int GEMM_LDS = 3 * 48 * 1024;  // 147456 B
  static bool s_attr = false;
  if (!s_attr) {
    s_attr = true;
    (void)hipFuncSetAttribute(reinterpret_cast<const void*>(gemm_kernel<0>),
                              hipFuncAttributeMaxDynamicSharedMemorySize,
                              GEMM_LDS);
    (void)hipFuncSetAttribute(reinterpret_cast<const void*>(gemm_kernel<1>),
                              hipFuncAttributeMaxDynamicSharedMemorySize,
                              GEMM_LDS);
  }

  cvt_all_kernel<<<dim3(8192), dim3(256), 0, stream>>>(
      x, WQ, WK, WV, WO, xb, wqt, wkt, wvt, wot);
  gemm_kernel<0><<<dim3(768), dim3(512), GEMM_LDS, stream>>>(
      xb, wqt, wkt, wvt, Qb, Kb, Vtb, nullptr, nullptr);
  attn_kernel<<<dim3(512), dim3(256), 0, stream>>>(Qb, Kb, Vtb, ctxb);
  gemm_kernel<1><<<dim3(256), dim3(512), GEMM_LDS, stream>>>(
      ctxb, wot, nullptr, nullptr, nullptr, nullptr, nullptr, x, out);
  ln_kernel<<<dim3(8192), dim3(256), 0, stream>>>(out, gamma, beta);
}